// Round 6
// baseline (166.265 us; speedup 1.0000x reference)
//
#include <hip/hip_runtime.h>
#include <cstddef>

#define B_     4096
#define L_     64
#define OUT_   64
#define KS_    8
#define KK_    4
#define LOUT_  57
#define C_     3648      // OUT_*LOUT_ = 57*64
#define HID_   33
#define TEMP_  34.0f
#define EPS_   1e-5f
#define NCH_   128       // b-chunks for stats (32 rows each)
#define SROWS_ 32        // rows per stats block
#define NB2_   32        // rows per block in write kernel

// gelu tanh-form: x * sigmoid(1.5957691*x*(1+0.044715x^2)); max abs err ~5e-4.
__device__ __forceinline__ float gelu_f(float x) {
    float e = exp2f(-2.3022083f * x * fmaf(0.044715f * x, x, 1.0f));
    return x * __builtin_amdgcn_rcpf(1.0f + e);
}

// Stage ROWS rows of x into 4 byte-shifted LDS copies:
//   xs4[s][r][t] = float4{ x[r][4t+s..4t+s+3] }
// window x[r][l..l+7] = slots (l>>2), (l>>2)+1 of copy (l&3): 2 ds_read_b128.
template<int ROWS>
__device__ __forceinline__ void stage_shifted(
    const float* __restrict__ x, int b0, int tid,
    float4 (*xs4)[ROWS][17])
{
    for (int idx = tid; idx < ROWS * 16; idx += 256) {
        int r = idx >> 4, t = idx & 15;
        const float4* xrow = (const float4*)(x + (size_t)(b0 + r) * L_);
        float4 a  = xrow[t];
        float4 bq = xrow[t < 15 ? t + 1 : 15];
        xs4[0][r][t] = a;
        xs4[1][r][t] = make_float4(a.y, a.z, a.w, bq.x);
        xs4[2][r][t] = make_float4(a.z, a.w, bq.x, bq.y);
        xs4[3][r][t] = make_float4(a.w, bq.x, bq.y, bq.z);
    }
}

// ---------------- kernel 1: fused attention + batch statistics ----------------
// grid (15 c-tiles, NCH_ b-chunks of 32 rows).
// Phase A: stage x. Phase B: attn inline (8 threads per row across HID_).
// Phase C: conv/gelu stats accumulate; partials to P.
__global__ __launch_bounds__(256) void stats_kernel(
    const float* __restrict__ x, const float* __restrict__ fc1_w,
    const float* __restrict__ fc2_w, const float* __restrict__ fc2_b,
    const float* __restrict__ weight, const float* __restrict__ bias,
    float* __restrict__ attn_out, float* __restrict__ P, int use_partial)
{
    int cb = blockIdx.x;
    int chunk = blockIdx.y;
    int tid = threadIdx.x;
    int c = cb * 256 + tid;
    bool act = c < C_;
    int o = act ? (c / LOUT_) : 0;
    int l = act ? (c - o * LOUT_) : 0;
    int q = l >> 2, s = l & 3;

    float w[KK_][KS_];
    float bk[KK_];
    #pragma unroll
    for (int k = 0; k < KK_; ++k) {
        bk[k] = bias[k * OUT_ + o];
        #pragma unroll
        for (int cq = 0; cq < KS_; ++cq) w[k][cq] = weight[(k * OUT_ + o) * KS_ + cq];
    }

    __shared__ float4 xs4[4][SROWS_][17];
    __shared__ float at[SROWS_][KK_];

    int b0 = chunk * SROWS_;
    stage_shifted<SROWS_>(x, b0, tid, xs4);
    __syncthreads();

    // ---- attn inline: row r = tid>>3, 8 threads (j) split the hidden units ----
    {
        int r = tid >> 3, j = tid & 7;
        float lg0 = 0.f, lg1 = 0.f, lg2 = 0.f, lg3 = 0.f;
        const float4* xr4 = &xs4[0][r][0];
        for (int h = j; h < HID_; h += 8) {
            const float4* f4 = (const float4*)(fc1_w + (size_t)h * L_);
            float acc = 0.f;
            #pragma unroll
            for (int i = 0; i < L_ / 4; ++i) {
                float4 xv = xr4[i];
                float4 wv = f4[i];
                acc = fmaf(xv.x, wv.x, acc);
                acc = fmaf(xv.y, wv.y, acc);
                acc = fmaf(xv.z, wv.z, acc);
                acc = fmaf(xv.w, wv.w, acc);
            }
            float a = gelu_f(acc);
            lg0 = fmaf(a, fc2_w[0 * HID_ + h], lg0);
            lg1 = fmaf(a, fc2_w[1 * HID_ + h], lg1);
            lg2 = fmaf(a, fc2_w[2 * HID_ + h], lg2);
            lg3 = fmaf(a, fc2_w[3 * HID_ + h], lg3);
        }
        #pragma unroll
        for (int mask = 1; mask < 8; mask <<= 1) {
            lg0 += __shfl_xor(lg0, mask, 8);
            lg1 += __shfl_xor(lg1, mask, 8);
            lg2 += __shfl_xor(lg2, mask, 8);
            lg3 += __shfl_xor(lg3, mask, 8);
        }
        if (j == 0) {
            float z0 = (lg0 + fc2_b[0]) * (1.0f / TEMP_);
            float z1 = (lg1 + fc2_b[1]) * (1.0f / TEMP_);
            float z2 = (lg2 + fc2_b[2]) * (1.0f / TEMP_);
            float z3 = (lg3 + fc2_b[3]) * (1.0f / TEMP_);
            float mx = fmaxf(fmaxf(z0, z1), fmaxf(z2, z3));
            float e0 = __expf(z0 - mx), e1 = __expf(z1 - mx);
            float e2 = __expf(z2 - mx), e3 = __expf(z3 - mx);
            float inv = __builtin_amdgcn_rcpf(e0 + e1 + e2 + e3);
            float a0 = e0 * inv, a1 = e1 * inv, a2 = e2 * inv, a3 = e3 * inv;
            at[r][0] = a0; at[r][1] = a1; at[r][2] = a2; at[r][3] = a3;
            if (cb == 0) {
                float4* ap = (float4*)(attn_out + (size_t)(b0 + r) * KK_);
                *ap = make_float4(a0, a1, a2, a3);
            }
        }
    }
    __syncthreads();

    // ---- stats ----
    float s1 = 0.f, s2 = 0.f, t1 = 0.f, t2 = 0.f;
    if (act) {
        const float4* base = &xs4[s][0][q];
        #pragma unroll 4
        for (int r = 0; r < SROWS_; ++r) {
            float4 A  = base[(size_t)r * 17];
            float4 Bv = base[(size_t)r * 17 + 1];
            float xw[8] = {A.x, A.y, A.z, A.w, Bv.x, Bv.y, Bv.z, Bv.w};
            float kv0 = bk[0], kv1 = bk[1], kv2 = bk[2], kv3 = bk[3];
            #pragma unroll
            for (int cq = 0; cq < KS_; ++cq) {
                float xv = xw[cq];
                kv0 = fmaf(xv, w[0][cq], kv0);
                kv1 = fmaf(xv, w[1][cq], kv1);
                kv2 = fmaf(xv, w[2][cq], kv2);
                kv3 = fmaf(xv, w[3][cq], kv3);
            }
            float ov = at[r][0] * kv0;
            ov = fmaf(at[r][1], kv1, ov);
            ov = fmaf(at[r][2], kv2, ov);
            ov = fmaf(at[r][3], kv3, ov);
            float g = gelu_f(ov);
            s1 += g; s2 = fmaf(g, g, s2);
            float g0 = gelu_f(kv0), g1 = gelu_f(kv1), g2 = gelu_f(kv2), g3 = gelu_f(kv3);
            t1 += g0 + g1 + g2 + g3;
            t2 = fmaf(g0, g0, t2); t2 = fmaf(g1, g1, t2);
            t2 = fmaf(g2, g2, t2); t2 = fmaf(g3, g3, t2);
        }
    }
    if (!act) return;
    if (use_partial) {
        size_t base = (size_t)chunk * 4 * C_ + c;
        P[base]          = s1;
        P[base + C_]     = s2;
        P[base + 2 * C_] = t1;
        P[base + 3 * C_] = t2;
    } else {
        atomicAdd(&P[c], s1);
        atomicAdd(&P[C_ + c], s2);
        atomicAdd(&P[2 * C_ + c], t1);
        atomicAdd(&P[3 * C_ + c], t2);
    }
}

// ---------------- kernel 2: reduce partials, fold into scale/shift ----------------
__global__ __launch_bounds__(256) void finalize_kernel(
    const float* __restrict__ P, const float* __restrict__ gamma,
    const float* __restrict__ beta, float* __restrict__ F, int use_partial)
{
    __shared__ float red[4][64];
    int t = threadIdx.x;
    int cl = t & 63;
    int s = t >> 6;
    int c = blockIdx.x * 64 + cl;    // C_ = 57*64, always in range
    float a = 0.f;
    if (use_partial) {
        for (int ch = 0; ch < NCH_; ++ch)
            a += P[((size_t)ch * 4 + s) * C_ + c];
    } else {
        a = P[(size_t)s * C_ + c];
    }
    red[s][cl] = a;
    __syncthreads();
    if (t < 64) {
        float a0 = red[0][cl], a1 = red[1][cl], a2 = red[2][cl], a3 = red[3][cl];
        float m  = a0 * (1.0f / B_);
        float v  = a1 * (1.0f / B_) - m * m;
        float rs = rsqrtf(v + EPS_);
        float m2 = a2 * (1.0f / (B_ * KK_));
        float v2 = a3 * (1.0f / (B_ * KK_)) - m2 * m2;
        float rs2 = rsqrtf(v2 + EPS_);
        float ga = gamma[c], be = beta[c];
        F[c]          = rs * ga;             // scaleA
        F[C_ + c]     = be - m * rs * ga;    // shiftA
        F[2 * C_ + c] = rs2 * ga;            // scaleK
        F[3 * C_ + c] = be - m2 * rs2 * ga;  // shiftK
    }
}

// ---------------- kernel 3: recompute + normalize + write ----------------
__global__ __launch_bounds__(256) void write_kernel(
    const float* __restrict__ x, const float* __restrict__ weight,
    const float* __restrict__ bias, const float* __restrict__ attn,
    const float* __restrict__ F,
    float* __restrict__ out0, float* __restrict__ kwout)
{
    int cc = blockIdx.x;    // 0..14
    int bg = blockIdx.y;    // 0..B/NB2_-1
    int tid = threadIdx.x;
    int c = cc * 256 + tid;
    bool act = c < C_;
    int o = act ? (c / LOUT_) : 0;
    int l = act ? (c - o * LOUT_) : 0;
    int q = l >> 2, s = l & 3;

    float w[KK_][KS_];
    float bk[KK_];
    #pragma unroll
    for (int k = 0; k < KK_; ++k) {
        bk[k] = bias[k * OUT_ + o];
        #pragma unroll
        for (int cq = 0; cq < KS_; ++cq) w[k][cq] = weight[(k * OUT_ + o) * KS_ + cq];
    }
    float sA = 0.f, hA = 0.f, sK = 0.f, hK = 0.f;
    if (act) {
        sA = F[c]; hA = F[C_ + c]; sK = F[2 * C_ + c]; hK = F[3 * C_ + c];
    }

    __shared__ float4 xs4[4][NB2_][17];
    __shared__ float at[NB2_][KK_];
    int b0 = bg * NB2_;
    stage_shifted<NB2_>(x, b0, tid, xs4);
    if (tid < NB2_ * KK_) ((float*)at)[tid] = attn[(size_t)b0 * KK_ + tid];
    __syncthreads();

    if (!act) return;

    const float4* xbase = &xs4[s][0][q];
    #pragma unroll 4
    for (int r = 0; r < NB2_; ++r) {
        float4 A  = xbase[(size_t)r * 17];
        float4 Bv = xbase[(size_t)r * 17 + 1];
        float xw[8] = {A.x, A.y, A.z, A.w, Bv.x, Bv.y, Bv.z, Bv.w};
        float kv0 = bk[0], kv1 = bk[1], kv2 = bk[2], kv3 = bk[3];
        #pragma unroll
        for (int cq = 0; cq < KS_; ++cq) {
            float xv = xw[cq];
            kv0 = fmaf(xv, w[0][cq], kv0);
            kv1 = fmaf(xv, w[1][cq], kv1);
            kv2 = fmaf(xv, w[2][cq], kv2);
            kv3 = fmaf(xv, w[3][cq], kv3);
        }
        float ov = at[r][0] * kv0;
        ov = fmaf(at[r][1], kv1, ov);
        ov = fmaf(at[r][2], kv2, ov);
        ov = fmaf(at[r][3], kv3, ov);
        int b = b0 + r;
        float g = gelu_f(ov);
        out0[(size_t)b * C_ + c] = fmaf(g, sA, hA);
        float g0 = gelu_f(kv0), g1 = gelu_f(kv1), g2v = gelu_f(kv2), g3 = gelu_f(kv3);
        float* base = kwout + (size_t)b * KK_ * C_ + c;
        base[0]      = fmaf(g0,  sK, hK);
        base[C_]     = fmaf(g1,  sK, hK);
        base[2 * C_] = fmaf(g2v, sK, hK);
        base[3 * C_] = fmaf(g3,  sK, hK);
    }
}

extern "C" void kernel_launch(void* const* d_in, const int* in_sizes, int n_in,
                              void* d_out, int out_size, void* d_ws, size_t ws_size,
                              hipStream_t stream) {
    const float* x      = (const float*)d_in[0];
    const float* fc1_w  = (const float*)d_in[1];
    const float* fc2_w  = (const float*)d_in[2];
    const float* fc2_b  = (const float*)d_in[3];
    const float* weight = (const float*)d_in[4];
    const float* bias   = (const float*)d_in[5];
    const float* gamma  = (const float*)d_in[6];
    const float* beta   = (const float*)d_in[7];

    float* out  = (float*)d_out;
    float* out0 = out;                          // B*C
    float* attn = out + (size_t)B_ * C_;        // B*K
    float* kwout = attn + (size_t)B_ * KK_;     // B*K*C

    // ws layout: P (NCH_*4*C_ partials) then F (4*C_); atomic fallback uses 4*C_ + F.
    size_t need = (size_t)(NCH_ * 4 + 4) * C_ * sizeof(float);
    int use_partial = ws_size >= need;
    float* P = (float*)d_ws;
    float* F = P + (use_partial ? (size_t)NCH_ * 4 * C_ : (size_t)4 * C_);
    if (!use_partial)
        hipMemsetAsync(P, 0, 4 * C_ * sizeof(float), stream);

    stats_kernel<<<dim3((C_ + 255) / 256, NCH_), 256, 0, stream>>>(
        x, fc1_w, fc2_w, fc2_b, weight, bias, attn, P, use_partial);
    finalize_kernel<<<C_ / 64, 256, 0, stream>>>(P, gamma, beta, F, use_partial);
    write_kernel<<<dim3((C_ + 255) / 256, B_ / NB2_), 256, 0, stream>>>(
        x, weight, bias, attn, F, out0, kwout);
}

// Round 7
// 159.650 us; speedup vs baseline: 1.0414x; 1.0414x over previous
//
#include <hip/hip_runtime.h>
#include <cstddef>

#define B_     4096
#define L_     64
#define OUT_   64
#define KS_    8
#define KK_    4
#define LOUT_  57
#define C_     3648      // OUT_*LOUT_ = 57*64
#define HID_   33
#define TEMP_  34.0f
#define EPS_   1e-5f
#define NCH_   128       // b-chunks for stats (32 rows each)
#define SROWS_ 32        // rows per stats block
#define NB2_   32        // rows per block in write kernel

// gelu tanh-form: x * sigmoid(1.5957691*x*(1+0.044715x^2)); max abs err ~5e-4.
__device__ __forceinline__ float gelu_f(float x) {
    float e = exp2f(-2.3022083f * x * fmaf(0.044715f * x, x, 1.0f));
    return x * __builtin_amdgcn_rcpf(1.0f + e);
}

// ---------------- kernel 1: attention weights + xg window table ----------------
// xg[b][l] = float4{ x[b][l..l+3] }, l=0..60; window x[l..l+7] = xg[b][l], xg[b][l+4].
__global__ __launch_bounds__(128) void attn_kernel(
    const float* __restrict__ x, const float* __restrict__ fc1_w,
    const float* __restrict__ fc2_w, const float* __restrict__ fc2_b,
    float* __restrict__ attn_out, float4* __restrict__ xg)
{
    __shared__ float fc1s[HID_][L_];
    __shared__ float fc2s[KK_][HID_];
    __shared__ float fc2bs[KK_];
    int tid = threadIdx.x;
    for (int i = tid; i < HID_ * L_; i += 128) fc1s[i / L_][i % L_] = fc1_w[i];
    for (int i = tid; i < KK_ * HID_; i += 128) fc2s[i / HID_][i % HID_] = fc2_w[i];
    if (tid < KK_) fc2bs[tid] = fc2_b[tid];
    __syncthreads();

    int b = blockIdx.x * 128 + tid;

    float xr[L_];
    const float4* xp = (const float4*)(x + (size_t)b * L_);
    #pragma unroll
    for (int i = 0; i < L_ / 4; ++i) {
        float4 v = xp[i];
        xr[4*i] = v.x; xr[4*i+1] = v.y; xr[4*i+2] = v.z; xr[4*i+3] = v.w;
    }
    float logit[KK_] = {0.f, 0.f, 0.f, 0.f};
    for (int h = 0; h < HID_; ++h) {
        const float4* fr = (const float4*)&fc1s[h][0];
        float acc = 0.f;
        #pragma unroll
        for (int i = 0; i < L_ / 4; ++i) {
            float4 wv = fr[i];
            acc = fmaf(xr[4*i],   wv.x, acc);
            acc = fmaf(xr[4*i+1], wv.y, acc);
            acc = fmaf(xr[4*i+2], wv.z, acc);
            acc = fmaf(xr[4*i+3], wv.w, acc);
        }
        float a = gelu_f(acc);
        #pragma unroll
        for (int k = 0; k < KK_; ++k) logit[k] = fmaf(a, fc2s[k][h], logit[k]);
    }
    float z[KK_];
    #pragma unroll
    for (int k = 0; k < KK_; ++k) z[k] = (logit[k] + fc2bs[k]) * (1.0f / TEMP_);
    float mx = fmaxf(fmaxf(z[0], z[1]), fmaxf(z[2], z[3]));
    float e[KK_]; float s = 0.f;
    #pragma unroll
    for (int k = 0; k < KK_; ++k) { e[k] = __expf(z[k] - mx); s += e[k]; }
    float inv = __builtin_amdgcn_rcpf(s);
    #pragma unroll
    for (int k = 0; k < KK_; ++k) attn_out[(size_t)b * KK_ + k] = e[k] * inv;

    // ---- build xg for this block's 128 rows (coalesced: lanes = consecutive l) ----
    int b0 = blockIdx.x * 128;
    for (int idx = tid; idx < 128 * 64; idx += 128) {
        int rr = idx >> 6, l = idx & 63;
        if (l < 61) {
            const float* xrow = x + (size_t)(b0 + rr) * L_;
            xg[(size_t)(b0 + rr) * 64 + l] =
                make_float4(xrow[l], xrow[l+1], xrow[l+2], xrow[l+3]);
        }
    }
}

// ---------------- kernel 2: batch statistics (no x LDS; xg loads, L2-hot) ----------------
__global__ __launch_bounds__(256) void stats_kernel(
    const float4* __restrict__ xg, const float* __restrict__ weight,
    const float* __restrict__ bias, const float* __restrict__ attn,
    float* __restrict__ P, int use_partial)
{
    int cb = blockIdx.x;
    int chunk = blockIdx.y;
    int tid = threadIdx.x;
    int c = cb * 256 + tid;
    bool act = c < C_;
    int o = act ? (c / LOUT_) : 0;
    int l = act ? (c - o * LOUT_) : 0;

    float w[KK_][KS_];
    float bk[KK_];
    #pragma unroll
    for (int k = 0; k < KK_; ++k) {
        bk[k] = bias[k * OUT_ + o];
        #pragma unroll
        for (int cq = 0; cq < KS_; ++cq) w[k][cq] = weight[(k * OUT_ + o) * KS_ + cq];
    }

    __shared__ float at[SROWS_][KK_];
    int b0 = chunk * SROWS_;
    if (tid < SROWS_ * KK_) ((float*)at)[tid] = attn[(size_t)b0 * KK_ + tid];
    __syncthreads();

    float s1 = 0.f, s2 = 0.f, t1 = 0.f, t2 = 0.f;
    if (act) {
        const float4* p = xg + (size_t)b0 * 64 + l;
        #pragma unroll 4
        for (int r = 0; r < SROWS_; ++r) {
            float4 A  = p[(size_t)r * 64];
            float4 Bv = p[(size_t)r * 64 + 4];
            float4 atv = *(const float4*)&at[r][0];
            float xw[8] = {A.x, A.y, A.z, A.w, Bv.x, Bv.y, Bv.z, Bv.w};
            float kv0 = bk[0], kv1 = bk[1], kv2 = bk[2], kv3 = bk[3];
            #pragma unroll
            for (int cq = 0; cq < KS_; ++cq) {
                float xv = xw[cq];
                kv0 = fmaf(xv, w[0][cq], kv0);
                kv1 = fmaf(xv, w[1][cq], kv1);
                kv2 = fmaf(xv, w[2][cq], kv2);
                kv3 = fmaf(xv, w[3][cq], kv3);
            }
            float ov = atv.x * kv0;
            ov = fmaf(atv.y, kv1, ov);
            ov = fmaf(atv.z, kv2, ov);
            ov = fmaf(atv.w, kv3, ov);
            float g = gelu_f(ov);
            s1 += g; s2 = fmaf(g, g, s2);
            float g0 = gelu_f(kv0), g1 = gelu_f(kv1), g2 = gelu_f(kv2), g3 = gelu_f(kv3);
            t1 += g0 + g1 + g2 + g3;
            t2 = fmaf(g0, g0, t2); t2 = fmaf(g1, g1, t2);
            t2 = fmaf(g2, g2, t2); t2 = fmaf(g3, g3, t2);
        }
    }
    if (!act) return;
    if (use_partial) {
        size_t base = (size_t)chunk * 4 * C_ + c;
        P[base]          = s1;
        P[base + C_]     = s2;
        P[base + 2 * C_] = t1;
        P[base + 3 * C_] = t2;
    } else {
        atomicAdd(&P[c], s1);
        atomicAdd(&P[C_ + c], s2);
        atomicAdd(&P[2 * C_ + c], t1);
        atomicAdd(&P[3 * C_ + c], t2);
    }
}

// ---------------- kernel 3: reduce partials, fold into scale/shift ----------------
__global__ __launch_bounds__(256) void finalize_kernel(
    const float* __restrict__ P, const float* __restrict__ gamma,
    const float* __restrict__ beta, float* __restrict__ F, int use_partial)
{
    __shared__ float red[4][64];
    int t = threadIdx.x;
    int cl = t & 63;
    int s = t >> 6;
    int c = blockIdx.x * 64 + cl;    // C_ = 57*64, always in range
    float a = 0.f;
    if (use_partial) {
        for (int ch = 0; ch < NCH_; ++ch)
            a += P[((size_t)ch * 4 + s) * C_ + c];
    } else {
        a = P[(size_t)s * C_ + c];
    }
    red[s][cl] = a;
    __syncthreads();
    if (t < 64) {
        float a0 = red[0][cl], a1 = red[1][cl], a2 = red[2][cl], a3 = red[3][cl];
        float m  = a0 * (1.0f / B_);
        float v  = a1 * (1.0f / B_) - m * m;
        float rs = rsqrtf(v + EPS_);
        float m2 = a2 * (1.0f / (B_ * KK_));
        float v2 = a3 * (1.0f / (B_ * KK_)) - m2 * m2;
        float rs2 = rsqrtf(v2 + EPS_);
        float ga = gamma[c], be = beta[c];
        F[c]          = rs * ga;             // scaleA
        F[C_ + c]     = be - m * rs * ga;    // shiftA
        F[2 * C_ + c] = rs2 * ga;            // scaleK
        F[3 * C_ + c] = be - m2 * rs2 * ga;  // shiftK
    }
}

// ---------------- kernel 4: recompute + normalize + write ----------------
__global__ __launch_bounds__(256) void write_kernel(
    const float4* __restrict__ xg, const float* __restrict__ weight,
    const float* __restrict__ bias, const float* __restrict__ attn,
    const float* __restrict__ F,
    float* __restrict__ out0, float* __restrict__ kwout)
{
    int cc = blockIdx.x;    // 0..14
    int bg = blockIdx.y;    // 0..B/NB2_-1
    int tid = threadIdx.x;
    int c = cc * 256 + tid;
    bool act = c < C_;
    int o = act ? (c / LOUT_) : 0;
    int l = act ? (c - o * LOUT_) : 0;

    float w[KK_][KS_];
    float bk[KK_];
    #pragma unroll
    for (int k = 0; k < KK_; ++k) {
        bk[k] = bias[k * OUT_ + o];
        #pragma unroll
        for (int cq = 0; cq < KS_; ++cq) w[k][cq] = weight[(k * OUT_ + o) * KS_ + cq];
    }
    float sA = 0.f, hA = 0.f, sK = 0.f, hK = 0.f;
    if (act) {
        sA = F[c]; hA = F[C_ + c]; sK = F[2 * C_ + c]; hK = F[3 * C_ + c];
    }

    __shared__ float at[NB2_][KK_];
    int b0 = bg * NB2_;
    if (tid < NB2_ * KK_) ((float*)at)[tid] = attn[(size_t)b0 * KK_ + tid];
    __syncthreads();

    if (!act) return;

    const float4* p = xg + (size_t)b0 * 64 + l;
    #pragma unroll 4
    for (int r = 0; r < NB2_; ++r) {
        float4 A  = p[(size_t)r * 64];
        float4 Bv = p[(size_t)r * 64 + 4];
        float4 atv = *(const float4*)&at[r][0];
        float xw[8] = {A.x, A.y, A.z, A.w, Bv.x, Bv.y, Bv.z, Bv.w};
        float kv0 = bk[0], kv1 = bk[1], kv2 = bk[2], kv3 = bk[3];
        #pragma unroll
        for (int cq = 0; cq < KS_; ++cq) {
            float xv = xw[cq];
            kv0 = fmaf(xv, w[0][cq], kv0);
            kv1 = fmaf(xv, w[1][cq], kv1);
            kv2 = fmaf(xv, w[2][cq], kv2);
            kv3 = fmaf(xv, w[3][cq], kv3);
        }
        float ov = atv.x * kv0;
        ov = fmaf(atv.y, kv1, ov);
        ov = fmaf(atv.z, kv2, ov);
        ov = fmaf(atv.w, kv3, ov);
        int b = b0 + r;
        float g = gelu_f(ov);
        out0[(size_t)b * C_ + c] = fmaf(g, sA, hA);
        float g0 = gelu_f(kv0), g1 = gelu_f(kv1), g2v = gelu_f(kv2), g3 = gelu_f(kv3);
        float* base = kwout + (size_t)b * KK_ * C_ + c;
        base[0]      = fmaf(g0,  sK, hK);
        base[C_]     = fmaf(g1,  sK, hK);
        base[2 * C_] = fmaf(g2v, sK, hK);
        base[3 * C_] = fmaf(g3,  sK, hK);
    }
}

extern "C" void kernel_launch(void* const* d_in, const int* in_sizes, int n_in,
                              void* d_out, int out_size, void* d_ws, size_t ws_size,
                              hipStream_t stream) {
    const float* x      = (const float*)d_in[0];
    const float* fc1_w  = (const float*)d_in[1];
    const float* fc2_w  = (const float*)d_in[2];
    const float* fc2_b  = (const float*)d_in[3];
    const float* weight = (const float*)d_in[4];
    const float* bias   = (const float*)d_in[5];
    const float* gamma  = (const float*)d_in[6];
    const float* beta   = (const float*)d_in[7];

    float* out  = (float*)d_out;
    float* out0 = out;                          // B*C
    float* attn = out + (size_t)B_ * C_;        // B*K
    float* kwout = attn + (size_t)B_ * KK_;     // B*K*C

    // ws layout: xg (B*64 float4 = 4 MB) | P (NCH_*4*C_) | F (4*C_).
    float4* xg = (float4*)d_ws;
    float* P = (float*)d_ws + (size_t)B_ * 64 * 4;
    size_t need_partial = ((size_t)B_ * 64 * 4 + (size_t)(NCH_ * 4 + 4) * C_) * sizeof(float);
    int use_partial = ws_size >= need_partial;
    float* F = P + (use_partial ? (size_t)NCH_ * 4 * C_ : (size_t)4 * C_);
    if (!use_partial)
        hipMemsetAsync(P, 0, 4 * C_ * sizeof(float), stream);

    attn_kernel<<<B_ / 128, 128, 0, stream>>>(x, fc1_w, fc2_w, fc2_b, attn, xg);
    stats_kernel<<<dim3((C_ + 255) / 256, NCH_), 256, 0, stream>>>(
        xg, weight, bias, attn, P, use_partial);
    finalize_kernel<<<C_ / 64, 256, 0, stream>>>(P, gamma, beta, F, use_partial);
    write_kernel<<<dim3((C_ + 255) / 256, B_ / NB2_), 256, 0, stream>>>(
        xg, weight, bias, attn, F, out0, kwout);
}

// Round 8
// 143.305 us; speedup vs baseline: 1.1602x; 1.1141x over previous
//
#include <hip/hip_runtime.h>
#include <cstddef>

#define B_     4096
#define L_     64
#define OUT_   64
#define KS_    8
#define KK_    4
#define LOUT_  57
#define C_     3648      // OUT_*LOUT_ = 57*64
#define HID_   33
#define TEMP_  34.0f
#define EPS_   1e-5f
#define NCH_   128       // b-chunks for stats (32 rows each)
#define SROWS_ 32        // rows per stats block
#define NB2_   32        // rows per block in write kernel

typedef float f32x2 __attribute__((ext_vector_type(2)));

__device__ __forceinline__ f32x2 pk_fma(f32x2 a, f32x2 b, f32x2 c) {
    return __builtin_elementwise_fma(a, b, c);
}

// gelu tanh-form: x * sigmoid(1.5957691*x*(1+0.044715x^2)); max abs err ~5e-4.
__device__ __forceinline__ float gelu_f(float x) {
    float e = exp2f(-2.3022083f * x * fmaf(0.044715f * x, x, 1.0f));
    return x * __builtin_amdgcn_rcpf(1.0f + e);
}

// pairwise gelu: 5 packed VALU + 4 trans for two gelus.
__device__ __forceinline__ f32x2 gelu2(f32x2 x) {
    const f32x2 one = {1.f, 1.f};
    const f32x2 ca  = {0.044715f, 0.044715f};
    const f32x2 cb  = {-2.3022083f, -2.3022083f};
    f32x2 t = pk_fma(x * ca, x, one);        // 1 + a x^2
    f32x2 u = x * t * cb;
    f32x2 e = {exp2f(u.x), exp2f(u.y)};
    f32x2 d = e + one;
    f32x2 r = {__builtin_amdgcn_rcpf(d.x), __builtin_amdgcn_rcpf(d.y)};
    return x * r;
}

// Stage ROWS rows of x into 4 byte-shifted LDS copies:
//   xs4[s][r][t] = float4{ x[r][4t+s..4t+s+3] }
// window x[r][l..l+7] = slots (l>>2), (l>>2)+1 of copy (l&3): 2 ds_read_b128.
template<int ROWS>
__device__ __forceinline__ void stage_shifted(
    const float* __restrict__ x, int b0, int tid,
    float4 (*xs4)[ROWS][17])
{
    for (int idx = tid; idx < ROWS * 16; idx += 256) {
        int r = idx >> 4, t = idx & 15;
        const float4* xrow = (const float4*)(x + (size_t)(b0 + r) * L_);
        float4 a  = xrow[t];
        float4 bq = xrow[t < 15 ? t + 1 : 15];
        xs4[0][r][t] = a;
        xs4[1][r][t] = make_float4(a.y, a.z, a.w, bq.x);
        xs4[2][r][t] = make_float4(a.z, a.w, bq.x, bq.y);
        xs4[3][r][t] = make_float4(a.w, bq.x, bq.y, bq.z);
    }
}

// ---------------- kernel 1: attention weights ----------------
__global__ __launch_bounds__(128) void attn_kernel(
    const float* __restrict__ x, const float* __restrict__ fc1_w,
    const float* __restrict__ fc2_w, const float* __restrict__ fc2_b,
    float* __restrict__ attn_out)
{
    __shared__ float fc1s[HID_][L_];
    __shared__ float fc2s[KK_][HID_];
    __shared__ float fc2bs[KK_];
    int tid = threadIdx.x;
    for (int i = tid; i < HID_ * L_; i += 128) fc1s[i / L_][i % L_] = fc1_w[i];
    for (int i = tid; i < KK_ * HID_; i += 128) fc2s[i / HID_][i % HID_] = fc2_w[i];
    if (tid < KK_) fc2bs[tid] = fc2_b[tid];
    __syncthreads();

    int b = blockIdx.x * 128 + tid;

    float xr[L_];
    const float4* xp = (const float4*)(x + (size_t)b * L_);
    #pragma unroll
    for (int i = 0; i < L_ / 4; ++i) {
        float4 v = xp[i];
        xr[4*i] = v.x; xr[4*i+1] = v.y; xr[4*i+2] = v.z; xr[4*i+3] = v.w;
    }
    float logit[KK_] = {0.f, 0.f, 0.f, 0.f};
    for (int h = 0; h < HID_; ++h) {
        const float4* fr = (const float4*)&fc1s[h][0];
        float acc = 0.f;
        #pragma unroll
        for (int i = 0; i < L_ / 4; ++i) {
            float4 wv = fr[i];
            acc = fmaf(xr[4*i],   wv.x, acc);
            acc = fmaf(xr[4*i+1], wv.y, acc);
            acc = fmaf(xr[4*i+2], wv.z, acc);
            acc = fmaf(xr[4*i+3], wv.w, acc);
        }
        float a = gelu_f(acc);
        #pragma unroll
        for (int k = 0; k < KK_; ++k) logit[k] = fmaf(a, fc2s[k][h], logit[k]);
    }
    float z[KK_];
    #pragma unroll
    for (int k = 0; k < KK_; ++k) z[k] = (logit[k] + fc2bs[k]) * (1.0f / TEMP_);
    float mx = fmaxf(fmaxf(z[0], z[1]), fmaxf(z[2], z[3]));
    float e[KK_]; float s = 0.f;
    #pragma unroll
    for (int k = 0; k < KK_; ++k) { e[k] = __expf(z[k] - mx); s += e[k]; }
    float inv = __builtin_amdgcn_rcpf(s);
    #pragma unroll
    for (int k = 0; k < KK_; ++k) attn_out[(size_t)b * KK_ + k] = e[k] * inv;
}

// ---------------- kernel 2: batch statistics ----------------
__global__ __launch_bounds__(256) void stats_kernel(
    const float* __restrict__ x, const float* __restrict__ weight,
    const float* __restrict__ bias, const float* __restrict__ attn,
    float* __restrict__ P, int use_partial)
{
    int cb = blockIdx.x;
    int chunk = blockIdx.y;
    int tid = threadIdx.x;
    int c = cb * 256 + tid;
    bool act = c < C_;
    int o = act ? (c / LOUT_) : 0;
    int l = act ? (c - o * LOUT_) : 0;
    int q = l >> 2, s = l & 3;

    f32x2 wp[KK_][4];
    float bk[KK_];
    #pragma unroll
    for (int k = 0; k < KK_; ++k) {
        bk[k] = bias[k * OUT_ + o];
        const float* wk = weight + (size_t)(k * OUT_ + o) * KS_;
        #pragma unroll
        for (int j = 0; j < 4; ++j) wp[k][j] = f32x2{wk[2*j], wk[2*j+1]};
    }

    __shared__ float4 xs4[4][SROWS_][17];
    __shared__ float at[SROWS_][KK_];

    int b0 = chunk * SROWS_;
    stage_shifted<SROWS_>(x, b0, tid, xs4);
    if (tid < SROWS_ * KK_) ((float*)at)[tid] = attn[(size_t)b0 * KK_ + tid];
    __syncthreads();

    float s1 = 0.f, s2 = 0.f;
    f32x2 t1v = {0.f, 0.f}, t2v = {0.f, 0.f};
    if (act) {
        const float4* base = &xs4[s][0][q];
        #pragma unroll 4
        for (int r = 0; r < SROWS_; ++r) {
            float4 A  = base[(size_t)r * 17];
            float4 Bv = base[(size_t)r * 17 + 1];
            f32x2 xp[4] = {{A.x, A.y}, {A.z, A.w}, {Bv.x, Bv.y}, {Bv.z, Bv.w}};
            float kv[KK_];
            #pragma unroll
            for (int k = 0; k < KK_; ++k) {
                f32x2 acc = {bk[k], 0.f};
                #pragma unroll
                for (int j = 0; j < 4; ++j) acc = pk_fma(xp[j], wp[k][j], acc);
                kv[k] = acc.x + acc.y;
            }
            float ov = at[r][0] * kv[0];
            ov = fmaf(at[r][1], kv[1], ov);
            ov = fmaf(at[r][2], kv[2], ov);
            ov = fmaf(at[r][3], kv[3], ov);
            float g = gelu_f(ov);
            s1 += g; s2 = fmaf(g, g, s2);
            f32x2 g01 = gelu2(f32x2{kv[0], kv[1]});
            f32x2 g23 = gelu2(f32x2{kv[2], kv[3]});
            t1v = t1v + g01 + g23;
            t2v = pk_fma(g01, g01, t2v);
            t2v = pk_fma(g23, g23, t2v);
        }
    }
    if (!act) return;
    float t1 = t1v.x + t1v.y, t2 = t2v.x + t2v.y;
    if (use_partial) {
        size_t base = (size_t)chunk * 4 * C_ + c;
        P[base]          = s1;
        P[base + C_]     = s2;
        P[base + 2 * C_] = t1;
        P[base + 3 * C_] = t2;
    } else {
        atomicAdd(&P[c], s1);
        atomicAdd(&P[C_ + c], s2);
        atomicAdd(&P[2 * C_ + c], t1);
        atomicAdd(&P[3 * C_ + c], t2);
    }
}

// ---------------- kernel 3: reduce partials, fold into scale/shift ----------------
__global__ __launch_bounds__(256) void finalize_kernel(
    const float* __restrict__ P, const float* __restrict__ gamma,
    const float* __restrict__ beta, float* __restrict__ F, int use_partial)
{
    __shared__ float red[4][64];
    int t = threadIdx.x;
    int cl = t & 63;
    int s = t >> 6;
    int c = blockIdx.x * 64 + cl;    // C_ = 57*64, always in range
    float a = 0.f;
    if (use_partial) {
        for (int ch = 0; ch < NCH_; ++ch)
            a += P[((size_t)ch * 4 + s) * C_ + c];
    } else {
        a = P[(size_t)s * C_ + c];
    }
    red[s][cl] = a;
    __syncthreads();
    if (t < 64) {
        float a0 = red[0][cl], a1 = red[1][cl], a2 = red[2][cl], a3 = red[3][cl];
        float m  = a0 * (1.0f / B_);
        float v  = a1 * (1.0f / B_) - m * m;
        float rs = rsqrtf(v + EPS_);
        float m2 = a2 * (1.0f / (B_ * KK_));
        float v2 = a3 * (1.0f / (B_ * KK_)) - m2 * m2;
        float rs2 = rsqrtf(v2 + EPS_);
        float ga = gamma[c], be = beta[c];
        F[c]          = rs * ga;             // scaleA
        F[C_ + c]     = be - m * rs * ga;    // shiftA
        F[2 * C_ + c] = rs2 * ga;            // scaleK
        F[3 * C_ + c] = be - m2 * rs2 * ga;  // shiftK
    }
}

// ---------------- kernel 4: recompute + normalize + write ----------------
__global__ __launch_bounds__(256) void write_kernel(
    const float* __restrict__ x, const float* __restrict__ weight,
    const float* __restrict__ bias, const float* __restrict__ attn,
    const float* __restrict__ F,
    float* __restrict__ out0, float* __restrict__ kwout)
{
    int cc = blockIdx.x;    // 0..14
    int bg = blockIdx.y;    // 0..B/NB2_-1
    int tid = threadIdx.x;
    int c = cc * 256 + tid;
    bool act = c < C_;
    int o = act ? (c / LOUT_) : 0;
    int l = act ? (c - o * LOUT_) : 0;
    int q = l >> 2, s = l & 3;

    f32x2 wp[KK_][4];
    float bk[KK_];
    #pragma unroll
    for (int k = 0; k < KK_; ++k) {
        bk[k] = bias[k * OUT_ + o];
        const float* wk = weight + (size_t)(k * OUT_ + o) * KS_;
        #pragma unroll
        for (int j = 0; j < 4; ++j) wp[k][j] = f32x2{wk[2*j], wk[2*j+1]};
    }
    float sA = 0.f, hA = 0.f, sK = 0.f, hK = 0.f;
    if (act) {
        sA = F[c]; hA = F[C_ + c]; sK = F[2 * C_ + c]; hK = F[3 * C_ + c];
    }
    f32x2 sk2 = {sK, sK}, hk2 = {hK, hK};

    __shared__ float4 xs4[4][NB2_][17];
    __shared__ float at[NB2_][KK_];
    int b0 = bg * NB2_;
    stage_shifted<NB2_>(x, b0, tid, xs4);
    if (tid < NB2_ * KK_) ((float*)at)[tid] = attn[(size_t)b0 * KK_ + tid];
    __syncthreads();

    if (!act) return;

    const float4* xbase = &xs4[s][0][q];
    #pragma unroll 4
    for (int r = 0; r < NB2_; ++r) {
        float4 A  = xbase[(size_t)r * 17];
        float4 Bv = xbase[(size_t)r * 17 + 1];
        f32x2 xp[4] = {{A.x, A.y}, {A.z, A.w}, {Bv.x, Bv.y}, {Bv.z, Bv.w}};
        float kv[KK_];
        #pragma unroll
        for (int k = 0; k < KK_; ++k) {
            f32x2 acc = {bk[k], 0.f};
            #pragma unroll
            for (int j = 0; j < 4; ++j) acc = pk_fma(xp[j], wp[k][j], acc);
            kv[k] = acc.x + acc.y;
        }
        float ov = at[r][0] * kv[0];
        ov = fmaf(at[r][1], kv[1], ov);
        ov = fmaf(at[r][2], kv[2], ov);
        ov = fmaf(at[r][3], kv[3], ov);
        int b = b0 + r;
        float g = gelu_f(ov);
        out0[(size_t)b * C_ + c] = fmaf(g, sA, hA);
        f32x2 g01 = gelu2(f32x2{kv[0], kv[1]});
        f32x2 g23 = gelu2(f32x2{kv[2], kv[3]});
        f32x2 r01 = pk_fma(g01, sk2, hk2);
        f32x2 r23 = pk_fma(g23, sk2, hk2);
        float* base = kwout + (size_t)b * KK_ * C_ + c;
        base[0]      = r01.x;
        base[C_]     = r01.y;
        base[2 * C_] = r23.x;
        base[3 * C_] = r23.y;
    }
}

extern "C" void kernel_launch(void* const* d_in, const int* in_sizes, int n_in,
                              void* d_out, int out_size, void* d_ws, size_t ws_size,
                              hipStream_t stream) {
    const float* x      = (const float*)d_in[0];
    const float* fc1_w  = (const float*)d_in[1];
    const float* fc2_w  = (const float*)d_in[2];
    const float* fc2_b  = (const float*)d_in[3];
    const float* weight = (const float*)d_in[4];
    const float* bias   = (const float*)d_in[5];
    const float* gamma  = (const float*)d_in[6];
    const float* beta   = (const float*)d_in[7];

    float* out  = (float*)d_out;
    float* out0 = out;                          // B*C
    float* attn = out + (size_t)B_ * C_;        // B*K
    float* kwout = attn + (size_t)B_ * KK_;     // B*K*C

    // ws layout: P (NCH_*4*C_ partials) then F (4*C_); atomic fallback uses 4*C_ + F.
    size_t need = (size_t)(NCH_ * 4 + 4) * C_ * sizeof(float);
    int use_partial = ws_size >= need;
    float* P = (float*)d_ws;
    float* F = P + (use_partial ? (size_t)NCH_ * 4 * C_ : (size_t)4 * C_);
    if (!use_partial)
        hipMemsetAsync(P, 0, 4 * C_ * sizeof(float), stream);

    attn_kernel<<<B_ / 128, 128, 0, stream>>>(x, fc1_w, fc2_w, fc2_b, attn);
    stats_kernel<<<dim3((C_ + 255) / 256, NCH_), 256, 0, stream>>>(
        x, weight, bias, attn, P, use_partial);
    finalize_kernel<<<C_ / 64, 256, 0, stream>>>(P, gamma, beta, F, use_partial);
    write_kernel<<<dim3((C_ + 255) / 256, B_ / NB2_), 256, 0, stream>>>(
        x, weight, bias, attn, F, out0, kwout);
}